// Round 7
// baseline (321.380 us; speedup 1.0000x reference)
//
#include <hip/hip_runtime.h>
#include <hip/hip_bf16.h>

#define N_NODES 50000
#define N_EDGES 800000
#define D_IN 128
#define D_HID 512
#define D_OUT 128
#define CAT_DIM 640   // D_IN + D_HID
#define CAP 64        // per-node edge-bucket capacity (Poisson(16): P(>=64) ~ 1e-20)

typedef __attribute__((ext_vector_type(8))) short short8;
typedef __attribute__((ext_vector_type(4))) float floatx4;

__device__ __forceinline__ unsigned short f2bf(float f) {
    unsigned u = __float_as_uint(f);
    unsigned r = u + 0x7fffu + ((u >> 16) & 1u);   // RNE
    return (unsigned short)(r >> 16);
}

// ================= prep: casts/transposes/deg-zero/dtype-detect ============

#define PREP_CASTX_BLOCKS   6250   // 50000*128 elems / (256 thr * 4)
#define PREP_FCW_BLOCKS      256   // 128*512 / 256
#define PREP_W2_BLOCKS       320   // 640*128 / 256
#define PREP_DEG_BLOCKS      196   // ceil(50000/256)
#define PREP_TOTAL_BLOCKS  (PREP_CASTX_BLOCKS + PREP_FCW_BLOCKS + PREP_W2_BLOCKS + PREP_DEG_BLOCKS + 1)

__global__ void prep_kernel(const float* __restrict__ X, const float* __restrict__ fcW,
                            const float* __restrict__ Wm, const int* __restrict__ adj,
                            unsigned short* __restrict__ Xb,
                            unsigned short* __restrict__ fcwT,
                            unsigned short* __restrict__ WT,
                            int* __restrict__ deg, int* __restrict__ flag) {
    int b = blockIdx.x;
    int tid = threadIdx.x;
    if (b < PREP_CASTX_BLOCKS) {
        size_t base = ((size_t)b * 256 + tid) * 4;     // linear over 6.4M elems
        float4 v = *(const float4*)(X + base);
        unsigned short o[4] = { f2bf(v.x), f2bf(v.y), f2bf(v.z), f2bf(v.w) };
        *(unsigned long long*)(Xb + base) = *(unsigned long long*)o;
        return;
    }
    b -= PREP_CASTX_BLOCKS;
    if (b < PREP_FCW_BLOCKS) {
        int idx = b * 256 + tid;               // 128*512
        int k = idx >> 9;
        int n = idx & (D_HID - 1);
        fcwT[n * D_IN + k] = f2bf(fcW[idx]);
        return;
    }
    b -= PREP_FCW_BLOCKS;
    if (b < PREP_W2_BLOCKS) {
        int idx = b * 256 + tid;               // 640*128
        int k = idx >> 7;
        int n = idx & (D_OUT - 1);
        WT[n * CAT_DIM + k] = f2bf(Wm[idx]);
        return;
    }
    b -= PREP_W2_BLOCKS;
    if (b < PREP_DEG_BLOCKS) {
        int idx = b * 256 + tid;
        if (idx < N_NODES) deg[idx] = 0;
        return;
    }
    // detect (wave 0): int64 high words all zero (node ids < 2^31)
    if (tid < 64) {
        int v = adj[2 * tid + 1];
        unsigned long long m = __ballot(v != 0);
        if (tid == 0) *flag = (m == 0ULL) ? 2 : 1;   // 2 => int64 stride
    }
}

// ================= hist (device fn, fused into mid kernel) =================

__device__ __forceinline__ void hist_edges(const int* __restrict__ adj, int s, int e0,
                                           int* __restrict__ deg, int* __restrict__ edge_list) {
    int src0, src1, trg0, trg1;
    if (s == 2) {   // int64: edges e0,e0+1 -> adj dwords [2e0 .. 2e0+3], coalesced
        int4 vs = *(const int4*)(adj + 2 * (size_t)e0);
        int4 vt = *(const int4*)(adj + 2 * ((size_t)N_EDGES + e0));
        src0 = vs.x; src1 = vs.z;
        trg0 = vt.x; trg1 = vt.z;
    } else {        // int32
        int2 vs = *(const int2*)(adj + e0);
        int2 vt = *(const int2*)(adj + N_EDGES + e0);
        src0 = vs.x; src1 = vs.y;
        trg0 = vt.x; trg1 = vt.y;
    }
    int p0 = atomicAdd(&deg[src0], 1);
    if (p0 < CAP) edge_list[src0 * CAP + p0] = trg0;
    int p1 = atomicAdd(&deg[src1], 1);
    if (p1 < CAP) edge_list[src1 * CAP + p1] = trg1;
}

// ================= GEMM1 tile: BM=64, BN=128, BK=64, 2x2 waves =============

#define GPAD 8
#define SM64_BYTES ((64 + 128) * (64 + GPAD) * 2)

__device__ __forceinline__ void gemm1_tile(char* smem,
    const unsigned short* __restrict__ A,      // Xb [N][128]
    const unsigned short* __restrict__ Bt,     // fcwT [512][128]
    const float* __restrict__ bias,
    unsigned short* __restrict__ F, int bm, int bn)
{
    constexpr int BK = 64;
    typedef unsigned short Row[BK + GPAD];
    Row* As = (Row*)smem;
    Row* Bs = (Row*)(smem + 64 * (BK + GPAD) * 2);
    int tid = threadIdx.x;
    int lane = tid & 63, w = tid >> 6;
    int wm = (w >> 1) * 32, wn = (w & 1) * 64;
    int q = lane >> 4, l16 = lane & 15;
    floatx4 acc[2][4] = {};
    int ra = tid >> 2;            // A row 0..63
    int ca = (tid & 3) * 8;       // A col base; passes +0,+32
    int rb = tid >> 1;            // B row 0..127
    int cb = (tid & 1) * 8;       // B col base; passes +0,+16,+32,+48

    for (int k0 = 0; k0 < D_IN; k0 += BK) {
        {
            int gr = bm + ra;
            const unsigned short* ap = A + (size_t)gr * D_IN + k0 + ca;
            #pragma unroll
            for (int p = 0; p < 2; ++p) {
                uint4 va = make_uint4(0u, 0u, 0u, 0u);
                if (gr < N_NODES) va = *(const uint4*)(ap + p * 32);
                *(uint4*)(&As[ra][ca + p * 32]) = va;
            }
        }
        {
            const unsigned short* bp = Bt + (size_t)(bn + rb) * D_IN + k0 + cb;
            #pragma unroll
            for (int p = 0; p < 4; ++p)
                *(uint4*)(&Bs[rb][cb + p * 16]) = *(const uint4*)(bp + p * 16);
        }
        __syncthreads();
        #pragma unroll
        for (int ks = 0; ks < 2; ++ks) {
            short8 af[2], bf[4];
            #pragma unroll
            for (int mi = 0; mi < 2; ++mi)
                af[mi] = *(const short8*)(&As[wm + mi * 16 + l16][ks * 32 + q * 8]);
            #pragma unroll
            for (int ni = 0; ni < 4; ++ni)
                bf[ni] = *(const short8*)(&Bs[wn + ni * 16 + l16][ks * 32 + q * 8]);
            #pragma unroll
            for (int mi = 0; mi < 2; ++mi)
                #pragma unroll
                for (int ni = 0; ni < 4; ++ni)
                    acc[mi][ni] = __builtin_amdgcn_mfma_f32_16x16x32_bf16(af[mi], bf[ni], acc[mi][ni], 0, 0, 0);
        }
        __syncthreads();
    }

    #pragma unroll
    for (int mi = 0; mi < 2; ++mi) {
        #pragma unroll
        for (int ni = 0; ni < 4; ++ni) {
            #pragma unroll
            for (int r = 0; r < 4; ++r) {
                int row = bm + wm + mi * 16 + q * 4 + r;
                int col = bn + wn + ni * 16 + l16;
                if (row < N_NODES) {
                    float v = fmaxf(acc[mi][ni][r] + bias[col], 0.0f);
                    F[(size_t)row * D_HID + col] = f2bf(v);
                }
            }
        }
    }
}

// ================= fused mid: hist blocks + GEMM1 blocks ===================

#define HIST_VB     1563   // ceil((N_EDGES/2)/256)
#define GEMM1_MT     782   // ceil(50000/64)
#define GEMM1_TILES (GEMM1_MT * 4)

__global__ __launch_bounds__(256)
void mid_kernel(const int* __restrict__ adj, const int* __restrict__ flag,
                int* __restrict__ deg, int* __restrict__ edge_list,
                const unsigned short* __restrict__ Xb,
                const unsigned short* __restrict__ fcwT,
                const float* __restrict__ fcb,
                unsigned short* __restrict__ F) {
    if (blockIdx.x < HIST_VB) {
        int e0 = (blockIdx.x * 256 + threadIdx.x) * 2;
        if (e0 < N_EDGES) hist_edges(adj, flag[0], e0, deg, edge_list);
        return;
    }
    __shared__ char smem[SM64_BYTES];
    int tile = blockIdx.x - HIST_VB;
    gemm1_tile(smem, Xb, fcwT, fcb, F, (tile >> 2) * 64, (tile & 3) * 128);
}

// ================= fused aggregate + GEMM2 =================================
// Block owns 32 nodes. Phase 1: gather-max their neighbor F rows into LDS
// aggS[32][520] (pad 8 -> 2-way bank aliasing, free). Phase 2: barrier-free
// GEMM C[32][128] = [Xb | aggS] @ WT^T; A k<128 frags from Xb (global, L1),
// A k>=128 from aggS (LDS), B frags from WT (global, L2-hot; no staging).

#define AG_BM     32
#define AG_BLOCKS 1563   // ceil(50000/32)
#define APAD      8

__device__ __forceinline__ void fmax_bf16x8(float* acc, const uint4& p) {
    const unsigned* a = (const unsigned*)&p;
    #pragma unroll
    for (int j = 0; j < 4; ++j) {
        unsigned u = a[j];
        acc[2 * j]     = fmaxf(acc[2 * j],     __uint_as_float(u << 16));
        acc[2 * j + 1] = fmaxf(acc[2 * j + 1], __uint_as_float(u & 0xffff0000u));
    }
}

__global__ __launch_bounds__(256)
void aggemm_kernel(const unsigned short* __restrict__ F,
                   const int* __restrict__ deg,
                   const int* __restrict__ edge_list,
                   const unsigned short* __restrict__ Xb,
                   const unsigned short* __restrict__ WT,
                   float* __restrict__ out) {
    __shared__ unsigned short aggS[AG_BM][D_HID + APAD];
    int tid = threadIdx.x;
    int lane = tid & 63, wv = tid >> 6;
    int bm = blockIdx.x * AG_BM;

    // ---- phase 1: aggregate 8 nodes per wave into LDS ----
    for (int nn = 0; nn < 8; ++nn) {
        int lr = wv * 8 + nn;
        int node = bm + lr;
        if (node < N_NODES) {
            int d = deg[node];
            d = d < CAP ? d : CAP;
            const int* el = edge_list + node * CAP;
            float acc[8] = {0.f, 0.f, 0.f, 0.f, 0.f, 0.f, 0.f, 0.f};
            int i = 0;
            for (; i + 4 <= d; i += 4) {
                uint4 p0 = *(const uint4*)(F + (size_t)el[i]     * D_HID + lane * 8);
                uint4 p1 = *(const uint4*)(F + (size_t)el[i + 1] * D_HID + lane * 8);
                uint4 p2 = *(const uint4*)(F + (size_t)el[i + 2] * D_HID + lane * 8);
                uint4 p3 = *(const uint4*)(F + (size_t)el[i + 3] * D_HID + lane * 8);
                fmax_bf16x8(acc, p0);
                fmax_bf16x8(acc, p1);
                fmax_bf16x8(acc, p2);
                fmax_bf16x8(acc, p3);
            }
            for (; i < d; ++i) {
                uint4 p0 = *(const uint4*)(F + (size_t)el[i] * D_HID + lane * 8);
                fmax_bf16x8(acc, p0);
            }
            unsigned o[4];
            #pragma unroll
            for (int j = 0; j < 4; ++j) {
                unsigned lo = __float_as_uint(acc[2 * j]) >> 16;          // exact: maxima of bf16
                unsigned hi = __float_as_uint(acc[2 * j + 1]) & 0xffff0000u;
                o[j] = lo | hi;
            }
            *(uint4*)(&aggS[lr][lane * 8]) = *(uint4*)o;
        }
    }
    __syncthreads();

    // ---- phase 2: barrier-free GEMM ----
    int wm = (wv >> 1) * 16, wn = (wv & 1) * 64;
    int q = lane >> 4, l16 = lane & 15;
    floatx4 acc[4] = {};
    int arow = bm + wm + l16;

    #pragma unroll
    for (int k0 = 0; k0 < D_IN; k0 += 32) {       // X part: A from global Xb
        short8 af = {};
        if (arow < N_NODES) af = *(const short8*)(Xb + (size_t)arow * D_IN + k0 + q * 8);
        #pragma unroll
        for (int ni = 0; ni < 4; ++ni) {
            short8 bf = *(const short8*)(WT + (size_t)(wn + ni * 16 + l16) * CAT_DIM + k0 + q * 8);
            acc[ni] = __builtin_amdgcn_mfma_f32_16x16x32_bf16(af, bf, acc[ni], 0, 0, 0);
        }
    }
    #pragma unroll
    for (int k0 = 0; k0 < D_HID; k0 += 32) {      // agg part: A from LDS
        short8 af = *(const short8*)(&aggS[wm + l16][k0 + q * 8]);
        #pragma unroll
        for (int ni = 0; ni < 4; ++ni) {
            short8 bf = *(const short8*)(WT + (size_t)(wn + ni * 16 + l16) * CAT_DIM + D_IN + k0 + q * 8);
            acc[ni] = __builtin_amdgcn_mfma_f32_16x16x32_bf16(af, bf, acc[ni], 0, 0, 0);
        }
    }

    #pragma unroll
    for (int ni = 0; ni < 4; ++ni) {
        #pragma unroll
        for (int r = 0; r < 4; ++r) {
            int row = bm + wm + q * 4 + r;
            if (row < N_NODES)
                out[(size_t)row * D_OUT + wn + ni * 16 + l16] = acc[ni][r];
        }
    }
}

// ================= host launch =============================================

extern "C" void kernel_launch(void* const* d_in, const int* in_sizes, int n_in,
                              void* d_out, int out_size, void* d_ws, size_t ws_size,
                              hipStream_t stream) {
    const float* X    = (const float*)d_in[0];
    const float* fc_w = (const float*)d_in[1];
    const float* fc_b = (const float*)d_in[2];
    const float* Wm   = (const float*)d_in[3];
    const int*   adj  = (const int*)d_in[4];
    float* outp = (float*)d_out;

    char* ws = (char*)d_ws;
    size_t off = 0;
    auto alloc = [&](size_t bytes) -> void* {
        void* p = ws + off;
        off = (off + bytes + 255) & ~(size_t)255;
        return p;
    };
    unsigned short* Xb   = (unsigned short*)alloc((size_t)N_NODES * D_IN * 2);
    unsigned short* F    = (unsigned short*)alloc((size_t)N_NODES * D_HID * 2);
    unsigned short* fcwT = (unsigned short*)alloc((size_t)D_HID * D_IN * 2);
    unsigned short* WT   = (unsigned short*)alloc((size_t)D_OUT * CAT_DIM * 2);
    int* deg       = (int*)alloc((size_t)N_NODES * 4);
    int* edge_list = (int*)alloc((size_t)N_NODES * CAP * 4);
    int* flag      = (int*)alloc(256);

    prep_kernel<<<PREP_TOTAL_BLOCKS, 256, 0, stream>>>(X, fc_w, Wm, adj, Xb, fcwT, WT, deg, flag);
    mid_kernel<<<HIST_VB + GEMM1_TILES, 256, 0, stream>>>(adj, flag, deg, edge_list,
                                                          Xb, fcwT, fc_b, F);
    aggemm_kernel<<<AG_BLOCKS, 256, 0, stream>>>(F, deg, edge_list, Xb, WT, outp);
}